// Round 1
// baseline (90.380 us; speedup 1.0000x reference)
//
#include <hip/hip_runtime.h>
#include <math.h>

// SnakeLoss: x,target [B=64, N=1024, 2] fp32.
// shift_means[b,s] = (1/N) sum_j ||x[b,j] - target[b,(j-s)%N]||
// out = mean_b min_s shift_means[b,s]   (scalar fp32)
//
// Decomposition: every element of the BxNxN distance matrix belongs to exactly
// one shift s = (j-k)%N, so we compute 67M distances once, bucketed by s.
// Kernel 1: thread owns shift s, loops a 256-long j range -> no cross-thread
//           reduction in the hot loop. x[j] is wave-uniform (LDS broadcast,
//           free); target[(j-s)%N] is lane-consecutive (contiguous ds_read_b64).
//           Only the needed 511-wide target window is staged in LDS -> no mod
//           in the inner loop. Grid 64x4x4 = 1024 blocks = 4 blocks/CU.
// Kernel 2: per-b: sum 4 j-partials per s, min over s.
// Kernel 3: mean over b -> d_out[0].

#define BATCH 64
#define NPT   1024   // points per snake
#define SGRP  4      // shift groups  (256 shifts each = blockDim)
#define JGRP  4      // j groups      (256 j each)
#define TPB   256
#define JLEN  (NPT / JGRP)   // 256
#define WIN   512            // target window (needs 511, round up)

__global__ __launch_bounds__(TPB) void snake_partial(
    const float2* __restrict__ x, const float2* __restrict__ tgt,
    float* __restrict__ partial) {
  const int b   = blockIdx.x;
  const int sg  = blockIdx.y;
  const int jg  = blockIdx.z;
  const int tid = threadIdx.x;
  const int j0  = jg * JLEN;
  const int s0  = sg * TPB;

  __shared__ float2 t_lds[WIN];
  __shared__ float2 x_lds[JLEN];

  const float2* tb = tgt + b * NPT;
  const float2* xb = x   + b * NPT + j0;

  // window base: k = (j - s) mod N for j in [j0,j0+255], s in [s0,s0+255]
  // spans 511 consecutive values starting at j0 - s0 - 255 (mod N).
  const int kb = (j0 - s0 - 255) & (NPT - 1);
  for (int w = tid; w < WIN; w += TPB)
    t_lds[w] = tb[(kb + w) & (NPT - 1)];
  x_lds[tid] = xb[tid];
  __syncthreads();

  float acc = 0.f;
  const int off0 = 255 - tid;   // t_lds[off0 + jl] == target[(j - s) & (N-1)]
#pragma unroll 8
  for (int jl = 0; jl < JLEN; ++jl) {
    const float2 xv = x_lds[jl];          // wave-uniform -> LDS broadcast
    const float2 tv = t_lds[off0 + jl];   // lane-consecutive ds_read_b64
    const float dx = xv.x - tv.x;
    const float dy = xv.y - tv.y;
    acc += sqrtf(fmaf(dx, dx, dy * dy));
  }
  partial[(b * JGRP + jg) * NPT + s0 + tid] = acc;
}

__global__ __launch_bounds__(TPB) void snake_min(
    const float* __restrict__ partial, float* __restrict__ bmin) {
  const int b   = blockIdx.x;
  const int tid = threadIdx.x;
  float m = 3.4e38f;
  for (int si = 0; si < NPT / TPB; ++si) {
    const int s = si * TPB + tid;
    float tot = 0.f;
#pragma unroll
    for (int jg = 0; jg < JGRP; ++jg)
      tot += partial[(b * JGRP + jg) * NPT + s];
    m = fminf(m, tot);
  }
  // wave-64 shuffle min, then 4-wave LDS min
  for (int o = 32; o > 0; o >>= 1)
    m = fminf(m, __shfl_down(m, o));
  __shared__ float red[4];
  if ((tid & 63) == 0) red[tid >> 6] = m;
  __syncthreads();
  if (tid == 0)
    bmin[b] = fminf(fminf(red[0], red[1]), fminf(red[2], red[3]));
}

__global__ void snake_final(const float* __restrict__ bmin,
                            float* __restrict__ out) {
  float v = bmin[threadIdx.x];  // 64 threads = 1 wave
  for (int o = 32; o > 0; o >>= 1)
    v += __shfl_down(v, o);
  if (threadIdx.x == 0)
    out[0] = v * (1.0f / ((float)NPT * (float)BATCH));
}

extern "C" void kernel_launch(void* const* d_in, const int* in_sizes, int n_in,
                              void* d_out, int out_size, void* d_ws, size_t ws_size,
                              hipStream_t stream) {
  const float2* x   = (const float2*)d_in[0];
  const float2* tgt = (const float2*)d_in[1];
  float* partial = (float*)d_ws;                  // BATCH*JGRP*NPT floats = 1 MB
  float* bmin    = partial + BATCH * JGRP * NPT;  // 64 floats
  float* out     = (float*)d_out;

  dim3 g1(BATCH, SGRP, JGRP);
  snake_partial<<<g1, TPB, 0, stream>>>(x, tgt, partial);
  snake_min<<<BATCH, TPB, 0, stream>>>(partial, bmin);
  snake_final<<<1, 64, 0, stream>>>(bmin, out);
}

// Round 2
// 72.328 us; speedup vs baseline: 1.2496x; 1.2496x over previous
//
#include <hip/hip_runtime.h>
#include <math.h>

// SnakeLoss: x,target [B=64, N=1024, 2] fp32.
// shift_means[b,s] = (1/N) sum_j ||x[b,j] - target[b,(j-s)%N]||
// out = mean_b min_s shift_means[b,s]   (scalar fp32)
//
// V2 changes vs V1 (40 us -> predicted ~10-12 us for snake_partial):
//  - __builtin_amdgcn_sqrtf: raw v_sqrt_f32, drops the IEEE sqrtf fixup
//    sequence (~3x VALU per distance). Accuracy ~1 ulp, threshold is 3.4e-2.
//  - target staged as overlapping float4 pairs t4[w]=(t[w],t[w+1]):
//    one lane-contiguous conflict-free ds_read_b128 feeds 2 distances.
//  - x read from global with wave-uniform address (scalar SMEM path, off the
//    LDS pipe; inputs are L2-resident).
//  - 2 accumulators to break the acc+= dependency chain.

#define BATCH 64
#define NPT   1024   // points per snake
#define SGRP  4      // shift groups  (256 shifts each = blockDim)
#define JGRP  4      // j groups      (256 j each)
#define TPB   256
#define JLEN  (NPT / JGRP)   // 256
#define WIN   512            // target window entries (needs 511 float2)

__global__ __launch_bounds__(TPB) void snake_partial(
    const float2* __restrict__ x, const float2* __restrict__ tgt,
    float* __restrict__ partial) {
  const int b   = blockIdx.x;
  const int sg  = blockIdx.y;
  const int jg  = blockIdx.z;
  const int tid = threadIdx.x;
  const int j0  = jg * JLEN;
  const int s0  = sg * TPB;

  // t4[w] = (t_win[w], t_win[w+1]); t_win[w] = tgt[b][(kb+w) % N]
  __shared__ float4 t4[WIN];

  const float2* tb = tgt + b * NPT;
  // window base: k = (j - s) mod N spans 511 consecutive values from j0-s0-255
  const int kb = (j0 - s0 - 255) & (NPT - 1);
  for (int w = tid; w < WIN; w += TPB) {
    const float2 a = tb[(kb + w) & (NPT - 1)];
    const float2 c = tb[(kb + w + 1) & (NPT - 1)];
    t4[w] = make_float4(a.x, a.y, c.x, c.y);
  }
  __syncthreads();

  // x: wave-uniform address (no tid) -> scalar loads, no LDS traffic.
  const float4* xg = (const float4*)(x + b * NPT + j0);

  float acc0 = 0.f, acc1 = 0.f;
  const int off0 = 255 - tid;  // t4[off0+jl] = (t[(j-s)%N], t[(j+1-s)%N])
#pragma unroll 8
  for (int jl = 0; jl < JLEN; jl += 2) {
    const float4 tp = t4[off0 + jl];   // ds_read_b128, lane-contiguous
    const float4 xp = xg[jl >> 1];     // uniform: s_load_dwordx4
    const float dx0 = xp.x - tp.x, dy0 = xp.y - tp.y;
    const float dx1 = xp.z - tp.z, dy1 = xp.w - tp.w;
    acc0 += __builtin_amdgcn_sqrtf(fmaf(dx0, dx0, dy0 * dy0));
    acc1 += __builtin_amdgcn_sqrtf(fmaf(dx1, dx1, dy1 * dy1));
  }
  partial[(b * JGRP + jg) * NPT + s0 + tid] = acc0 + acc1;
}

__global__ __launch_bounds__(TPB) void snake_min(
    const float* __restrict__ partial, float* __restrict__ bmin) {
  const int b   = blockIdx.x;
  const int tid = threadIdx.x;
  float m = 3.4e38f;
  for (int si = 0; si < NPT / TPB; ++si) {
    const int s = si * TPB + tid;
    float tot = 0.f;
#pragma unroll
    for (int jg = 0; jg < JGRP; ++jg)
      tot += partial[(b * JGRP + jg) * NPT + s];
    m = fminf(m, tot);
  }
  for (int o = 32; o > 0; o >>= 1)
    m = fminf(m, __shfl_down(m, o));
  __shared__ float red[4];
  if ((tid & 63) == 0) red[tid >> 6] = m;
  __syncthreads();
  if (tid == 0)
    bmin[b] = fminf(fminf(red[0], red[1]), fminf(red[2], red[3]));
}

__global__ void snake_final(const float* __restrict__ bmin,
                            float* __restrict__ out) {
  float v = bmin[threadIdx.x];  // 64 threads = 1 wave
  for (int o = 32; o > 0; o >>= 1)
    v += __shfl_down(v, o);
  if (threadIdx.x == 0)
    out[0] = v * (1.0f / ((float)NPT * (float)BATCH));
}

extern "C" void kernel_launch(void* const* d_in, const int* in_sizes, int n_in,
                              void* d_out, int out_size, void* d_ws, size_t ws_size,
                              hipStream_t stream) {
  const float2* x   = (const float2*)d_in[0];
  const float2* tgt = (const float2*)d_in[1];
  float* partial = (float*)d_ws;                  // BATCH*JGRP*NPT floats = 1 MB
  float* bmin    = partial + BATCH * JGRP * NPT;  // 64 floats
  float* out     = (float*)d_out;

  dim3 g1(BATCH, SGRP, JGRP);
  snake_partial<<<g1, TPB, 0, stream>>>(x, tgt, partial);
  snake_min<<<BATCH, TPB, 0, stream>>>(partial, bmin);
  snake_final<<<1, 64, 0, stream>>>(bmin, out);
}

// Round 3
// 71.426 us; speedup vs baseline: 1.2654x; 1.0126x over previous
//
#include <hip/hip_runtime.h>
#include <math.h>

// SnakeLoss: x,target [B=64, N=1024, 2] fp32.
// shift_means[b,s] = (1/N) sum_j ||x[b,j] - target[b,(j-s)%N]||
// out = mean_b min_s shift_means[b,s]   (scalar fp32)
//
// V3: t-value sharing across G=4 shifts.
//   Thread owns shifts s_g = tid + 256g. For group g it processes j-values
//   offset by 256g, so the target index (j - s_g) mod N == j0 + jl - tid is
//   the SAME for all 4 groups -> one ds_read_b128 (overlapped t-pair) feeds
//   8 distances (2 B LDS/dist, was 8). x reads are wave-uniform scalar loads
//   (SMEM pipe). VALU is now the bottleneck: ~17 cyc/wave-dist -> ~7.3 us.

#define BATCH 64
#define NPT   1024
#define TPB   256
#define G     4              // shifts per thread (s = tid + 256g)
#define JGRP  16             // j chunks -> grid = 64*16 = 1024 blocks
#define JLEN  (NPT / JGRP)   // 64
#define TWIN  (JLEN + 256)   // 320 window entries (need 319)

__global__ __launch_bounds__(TPB) void snake_partial(
    const float2* __restrict__ x, const float2* __restrict__ tgt,
    float* __restrict__ partial) {
  const int b   = blockIdx.x;
  const int jg  = blockIdx.y;
  const int tid = threadIdx.x;
  const int j0  = jg * JLEN;

  // t4[w] = (t[(kb+w)%N], t[(kb+w+1)%N]), kb = j0-255: one b128 = 2 t-values.
  __shared__ float4 t4[TWIN];
  const float2* tb = tgt + b * NPT;
  const int kb = (j0 - 255) & (NPT - 1);
  for (int w = tid; w < TWIN; w += TPB) {
    const float2 a = tb[(kb + w) & (NPT - 1)];
    const float2 c = tb[(kb + w + 1) & (NPT - 1)];
    t4[w] = make_float4(a.x, a.y, c.x, c.y);
  }
  __syncthreads();

  // x chunk base per group: cg = (j0 + 256g) % N; chunks never wrap (64-long,
  // 64-aligned). Uniform addresses -> scalar loads, no LDS/VMEM-lane traffic.
  const float4* xg[G];
#pragma unroll
  for (int g = 0; g < G; ++g) {
    const int cg = (j0 + 256 * g) & (NPT - 1);
    xg[g] = (const float4*)(x + b * NPT + cg);
  }

  float2 acc[G];
#pragma unroll
  for (int g = 0; g < G; ++g) acc[g] = make_float2(0.f, 0.f);

  const int off0 = 255 - tid;  // t4[off0+jl] = (t[j0+jl-tid], t[j0+jl+1-tid])
#pragma unroll 4
  for (int jl = 0; jl < JLEN; jl += 2) {
    const float4 tp = t4[off0 + jl];  // shared by all 4 shift groups
#pragma unroll
    for (int g = 0; g < G; ++g) {
      const float4 xp = xg[g][jl >> 1];  // uniform: s_load_dwordx4
      const float dx0 = xp.x - tp.x, dy0 = xp.y - tp.y;
      const float dx1 = xp.z - tp.z, dy1 = xp.w - tp.w;
      acc[g].x += __builtin_amdgcn_sqrtf(fmaf(dx0, dx0, dy0 * dy0));
      acc[g].y += __builtin_amdgcn_sqrtf(fmaf(dx1, dx1, dy1 * dy1));
    }
  }

  float* prow = partial + (jg * BATCH + b) * NPT;  // s innermost: coalesced
#pragma unroll
  for (int g = 0; g < G; ++g)
    prow[tid + 256 * g] = acc[g].x + acc[g].y;
}

// grid (BATCH, 4): thread owns shift s = sg*256+tid; sum 16 jg-partials,
// block-min over 256 shifts -> bmin2[b*4+sg].
__global__ __launch_bounds__(TPB) void snake_min(
    const float* __restrict__ partial, float* __restrict__ bmin2) {
  const int b   = blockIdx.x;
  const int sg  = blockIdx.y;
  const int tid = threadIdx.x;
  const int s   = sg * TPB + tid;
  float tot = 0.f;
#pragma unroll
  for (int jg = 0; jg < JGRP; ++jg)
    tot += partial[(jg * BATCH + b) * NPT + s];
  float m = tot;
  for (int o = 32; o > 0; o >>= 1)
    m = fminf(m, __shfl_down(m, o));
  __shared__ float red[4];
  if ((tid & 63) == 0) red[tid >> 6] = m;
  __syncthreads();
  if (tid == 0)
    bmin2[b * 4 + sg] = fminf(fminf(red[0], red[1]), fminf(red[2], red[3]));
}

__global__ void snake_final(const float* __restrict__ bmin2,
                            float* __restrict__ out) {
  const int b = threadIdx.x;  // 64 threads = 1 wave
  float v = fminf(fminf(bmin2[b * 4 + 0], bmin2[b * 4 + 1]),
                  fminf(bmin2[b * 4 + 2], bmin2[b * 4 + 3]));
  for (int o = 32; o > 0; o >>= 1)
    v += __shfl_down(v, o);
  if (b == 0)
    out[0] = v * (1.0f / ((float)NPT * (float)BATCH));
}

extern "C" void kernel_launch(void* const* d_in, const int* in_sizes, int n_in,
                              void* d_out, int out_size, void* d_ws, size_t ws_size,
                              hipStream_t stream) {
  const float2* x   = (const float2*)d_in[0];
  const float2* tgt = (const float2*)d_in[1];
  float* partial = (float*)d_ws;                   // 16*64*1024 floats = 4 MB
  float* bmin2   = partial + JGRP * BATCH * NPT;   // 256 floats
  float* out     = (float*)d_out;

  dim3 g1(BATCH, JGRP);
  snake_partial<<<g1, TPB, 0, stream>>>(x, tgt, partial);
  dim3 g2(BATCH, 4);
  snake_min<<<g2, TPB, 0, stream>>>(partial, bmin2);
  snake_final<<<1, 64, 0, stream>>>(bmin2, out);
}